// Round 9
// baseline (226.498 us; speedup 1.0000x reference)
//
#include <hip/hip_runtime.h>
#include <math.h>

// Problem constants
#define NSLOT 64
#define ADIM  256
#define NE    16
#define NCLS  100
#define BATCH 256

// ws layout (float offsets)
#define OFF_QK 0u           // [16][256][4]  qk[e][a][l], pre-scaled by 1/16
#define OFF_CP 16384u       // [16]          log1p(count+1)
#define OFF_U  32768u       // [256*16][256] u[(b*16+e)][a]
#define OFF_Z  1081344u     // [4 kq][256*16][256] partial z
#define ZPART_STRIDE 1048576u

__device__ __forceinline__ float wmax(float v) {
#pragma unroll
  for (int m = 32; m >= 1; m >>= 1) v = fmaxf(v, __shfl_xor(v, m, 64));
  return v;
}
__device__ __forceinline__ float wsum(float v) {
#pragma unroll
  for (int m = 32; m >= 1; m >>= 1) v += __shfl_xor(v, m, 64);
  return v;
}

// ---------------- K1: qk[e][a][l] = (1/16) * sum_d q[e,l,d]*Wk[e,d,a]
__global__ __launch_bounds__(256) void prep_kernel(
    const float* __restrict__ queries, const float* __restrict__ Wk,
    const int* __restrict__ counts, float* __restrict__ qk, float* __restrict__ cp)
{
  __shared__ float smf[1024];       // [dg16][a16][l4]
  const int e  = blockIdx.x;
  const int as = blockIdx.y;
  const int tid = threadIdx.x;
  const int a_loc = tid & 15, dg = tid >> 4;
  const float* __restrict__ qp  = queries + e * 1024 + dg * 16;
  const float* __restrict__ wkp = Wk + (size_t)e * 65536 + (size_t)(dg * 16) * 256 + as * 16 + a_loc;
  float a0 = 0.f, a1 = 0.f, a2 = 0.f, a3 = 0.f;
#pragma unroll
  for (int dd = 0; dd < 16; ++dd) {
    float w = wkp[(size_t)dd * 256];
    a0 += qp[0 * 256 + dd] * w;
    a1 += qp[1 * 256 + dd] * w;
    a2 += qp[2 * 256 + dd] * w;
    a3 += qp[3 * 256 + dd] * w;
  }
  float4 acc; acc.x = a0; acc.y = a1; acc.z = a2; acc.w = a3;
  *(float4*)&smf[tid * 4] = acc;
  __syncthreads();
  if (tid < 64) {
    float s = 0.f;
#pragma unroll
    for (int g = 0; g < 16; ++g) s += smf[g * 64 + tid];
    qk[e * 1024 + as * 64 + tid] = s * 0.0625f;
  }
  if (e == 0 && as == 0 && tid < 16) cp[tid] = log1pf((float)counts[tid] + 1.0f);
}

// ---------------- K2: per (b, expert-half): scores -> softmax -> p -> u
// 512 blocks x 512 threads, 66KB LDS -> 2 blocks/CU = 4 waves/SIMD.
__global__ __launch_bounds__(512, 4) void attn_kernel(
    const float* __restrict__ x, const float* __restrict__ qk,
    float* __restrict__ U)
{
  __shared__ float Hs[64][256];   // chunk-swizzled: chunk c of row s at (c ^ (s&7))
  __shared__ float pt[64][8];
  const int tid  = threadIdx.x;
  const int lane = tid & 63;
  const int w    = tid >> 6;                 // 0..7
  const int i    = blockIdx.x;
  const int b    = i & 255;
  const int h    = i >> 8;                   // expert half

  const float4* __restrict__ x4 = (const float4*)(x + (size_t)b * 16384);
#pragma unroll
  for (int it = 0; it < 8; ++it) {
    int fidx = tid + it * 512;               // 0..4095 float4s
    int s = fidx >> 6, c = fidx & 63;
    *(float4*)&Hs[s][(c ^ (s & 7)) << 2] = x4[fidx];
  }
  __syncthreads();

  {
    const int e = __builtin_amdgcn_readfirstlane(h * 8 + w);
    const float* __restrict__ qe = qk + (size_t)e * 1024;
    float ac0 = 0.f, ac1 = 0.f, ac2 = 0.f, ac3 = 0.f;
#pragma unroll 4
    for (int a0 = 0; a0 < 64; ++a0) {
      float4 hh = *(const float4*)&Hs[lane][(a0 ^ (lane & 7)) << 2];
      const float4* __restrict__ qq = (const float4*)(qe + a0 * 16);
      float4 q0 = qq[0], q1 = qq[1], q2 = qq[2], q3 = qq[3];
      ac0 += hh.x*q0.x + hh.y*q1.x + hh.z*q2.x + hh.w*q3.x;
      ac1 += hh.x*q0.y + hh.y*q1.y + hh.z*q2.y + hh.w*q3.y;
      ac2 += hh.x*q0.z + hh.y*q1.z + hh.z*q2.z + hh.w*q3.z;
      ac3 += hh.x*q0.w + hh.y*q1.w + hh.z*q2.w + hh.w*q3.w;
    }
    float p = 0.f, m, ev;
    m = wmax(ac0); ev = __expf(ac0 - m); p += ev / wsum(ev);
    m = wmax(ac1); ev = __expf(ac1 - m); p += ev / wsum(ev);
    m = wmax(ac2); ev = __expf(ac2 - m); p += ev / wsum(ev);
    m = wmax(ac3); ev = __expf(ac3 - m); p += ev / wsum(ev);
    pt[lane][w] = p * 0.25f;
  }
  __syncthreads();

  {
    const int a = tid & 255, g = tid >> 8;
    const int hi = a >> 2, rem = a & 3;
    float u0 = 0.f, u1 = 0.f, u2 = 0.f, u3 = 0.f;
#pragma unroll 8
    for (int s = 0; s < 64; ++s) {
      float hv = Hs[s][(((hi ^ (s & 7)) << 2) | rem)];
      float4 p = *(const float4*)&pt[s][g * 4];
      u0 += hv * p.x; u1 += hv * p.y; u2 += hv * p.z; u3 += hv * p.w;
    }
    float* __restrict__ Ub = U + ((size_t)b * 16 + h * 8 + g * 4) * 256 + a;
    Ub[0 * 256] = u0; Ub[1 * 256] = u1; Ub[2 * 256] = u2; Ub[3 * 256] = u3;
  }
}

// ---------------- K3: per-expert GEMM, K-quartered (R3 structure, best measured).
// Zpart[kq] = U[:,kq*64:+64] @ Wv[:, same]^T. 64x64 tiles, acc[4][4] (8 fmac/ds_read).
// grid 1024: kq=i&3, dt=(i>>2)&3, bt=(i>>4)&3, e=i>>6. LDS 32KB -> 4 blocks/CU.
__global__ __launch_bounds__(256, 4) void zgemm_kernel(
    const float* __restrict__ U, const float* __restrict__ Wv,
    float* __restrict__ Zp)
{
  __shared__ float Us[64][64];   // chunk c of row r at (c ^ ((r>>2)&7))
  __shared__ float Ws[64][64];
  const int tid = threadIdx.x;
  const int i  = blockIdx.x;
  const int kq = i & 3, dt = (i >> 2) & 3, bt = (i >> 4) & 3, e = i >> 6;
  const int tx = tid & 15, ty = tid >> 4;
  float acc[4][4] = {};

#pragma unroll
  for (int it = 0; it < 4; ++it) {
    int t2 = tid + it * 256;           // 0..1023
    int row = t2 >> 4, c = t2 & 15;
    int cs = (c ^ ((row >> 2) & 7)) << 2;
    *(float4*)&Us[row][cs] =
      *(const float4*)&U[(((size_t)(bt * 64 + row)) * 16 + e) * 256 + kq * 64 + c * 4];
    *(float4*)&Ws[row][cs] =
      *(const float4*)&Wv[(size_t)e * 65536 + (size_t)(dt * 64 + row) * 256 + kq * 64 + c * 4];
  }
  __syncthreads();
#pragma unroll
  for (int cc = 0; cc < 16; ++cc) {
    float4 A[4], B[4];
#pragma unroll
    for (int ii = 0; ii < 4; ++ii) A[ii] = *(const float4*)&Us[ty * 4 + ii][(cc ^ (ty & 7)) << 2];
#pragma unroll
    for (int j = 0; j < 4; ++j) B[j] = *(const float4*)&Ws[tx * 4 + j][(cc ^ (tx & 7)) << 2];
#pragma unroll
    for (int ii = 0; ii < 4; ++ii)
#pragma unroll
      for (int j = 0; j < 4; ++j)
        acc[ii][j] += A[ii].x*B[j].x + A[ii].y*B[j].y + A[ii].z*B[j].z + A[ii].w*B[j].w;
  }
  float* __restrict__ Zk = Zp + (size_t)kq * ZPART_STRIDE;
#pragma unroll
  for (int ii = 0; ii < 4; ++ii) {
    float4 r; r.x = acc[ii][0]; r.y = acc[ii][1]; r.z = acc[ii][2]; r.w = acc[ii][3];
    *(float4*)&Zk[(((size_t)(bt * 64 + ty * 4 + ii)) * 16 + e) * 256 + dt * 64 + tx * 4] = r;
  }
}

// ---------------- K4: sum 4 partials -> norms -> top3 -> gate -> final -> logits
__global__ __launch_bounds__(512) void final_kernel(
    const float* __restrict__ Zp, const float* __restrict__ cp,
    const float* __restrict__ CQ, float* __restrict__ out)
{
  __shared__ float zs[16][260];
  __shared__ float nrm[16];
  __shared__ float fin[256];
  const int tid = threadIdx.x, lane = tid & 63, w = tid >> 6;  // 8 waves
  const int b = blockIdx.x;
  const size_t zb = (size_t)b * 16 * 256;

  // accumulate the 4 K-partials into LDS z: 1024 float4s / 512 thr = 2 each
#pragma unroll
  for (int it = 0; it < 2; ++it) {
    int idx = tid + it * 512;
    int e = idx >> 6, c = idx & 63;
    float4 v0 = *(const float4*)&Zp[0 * ZPART_STRIDE + zb + e * 256 + c * 4];
    float4 v1 = *(const float4*)&Zp[1 * ZPART_STRIDE + zb + e * 256 + c * 4];
    float4 v2 = *(const float4*)&Zp[2 * ZPART_STRIDE + zb + e * 256 + c * 4];
    float4 v3 = *(const float4*)&Zp[3 * ZPART_STRIDE + zb + e * 256 + c * 4];
    float4 r; r.x = v0.x+v1.x+v2.x+v3.x; r.y = v0.y+v1.y+v2.y+v3.y;
    r.z = v0.z+v1.z+v2.z+v3.z; r.w = v0.w+v1.w+v2.w+v3.w;
    *(float4*)&zs[e][c * 4] = r;
  }
  __syncthreads();

  for (int e = w; e < 16; e += 8) {
    float4 zv = *(const float4*)&zs[e][lane * 4];
    float ss = zv.x*zv.x + zv.y*zv.y + zv.z*zv.z + zv.w*zv.w;
    ss = wsum(ss);
    if (lane == 0) nrm[e] = sqrtf(ss);
  }
  __syncthreads();

  float sc[16];
#pragma unroll
  for (int e = 0; e < 16; ++e) sc[e] = nrm[e] * cp[e];
  int i0 = 0; float v0 = sc[0];
#pragma unroll
  for (int e = 1; e < 16; ++e) if (sc[e] > v0) { v0 = sc[e]; i0 = e; }
  int i1 = -1; float v1 = -3.4e38f;
#pragma unroll
  for (int e = 0; e < 16; ++e) if (e != i0 && sc[e] > v1) { v1 = sc[e]; i1 = e; }
  int i2 = -1; float v2 = -3.4e38f;
#pragma unroll
  for (int e = 0; e < 16; ++e) if (e != i0 && e != i1 && sc[e] > v2) { v2 = sc[e]; i2 = e; }
  float g1 = __expf(v1 - v0), g2 = __expf(v2 - v0);
  float inv = 1.0f / (1.0f + g1 + g2);
  float g0 = inv; g1 *= inv; g2 *= inv;

  if (tid < 256)
    fin[tid] = g0 * zs[i0][tid] + g1 * zs[i1][tid] + g2 * zs[i2][tid];
  __syncthreads();

  float4 f = *(const float4*)&fin[lane * 4];
  for (int c = w; c < NCLS; c += 8) {
    float4 cq = *(const float4*)&CQ[(size_t)c * 256 + lane * 4];
    float part = f.x*cq.x + f.y*cq.y + f.z*cq.z + f.w*cq.w;
    part = wsum(part);
    if (lane == 0) out[(size_t)b * NCLS + c] = part;
  }
}

extern "C" void kernel_launch(void* const* d_in, const int* in_sizes, int n_in,
                              void* d_out, int out_size, void* d_ws, size_t ws_size,
                              hipStream_t stream) {
  const float* x       = (const float*)d_in[0];
  const float* queries = (const float*)d_in[1];
  const float* Wk      = (const float*)d_in[2];
  const float* Wv      = (const float*)d_in[3];
  const float* CQ      = (const float*)d_in[4];
  const int*   counts  = (const int*)d_in[5];
  float* out = (float*)d_out;
  float* ws  = (float*)d_ws;
  float* qk = ws + OFF_QK;
  float* cp = ws + OFF_CP;
  float* U  = ws + OFF_U;
  float* Zp = ws + OFF_Z;

  prep_kernel<<<dim3(16, 16), 256, 0, stream>>>(queries, Wk, counts, qk, cp);
  attn_kernel<<<512, 512, 0, stream>>>(x, qk, U);
  zgemm_kernel<<<1024, 256, 0, stream>>>(U, Wv, Zp);
  final_kernel<<<256, 512, 0, stream>>>(Zp, cp, CQ, out);
}

// Round 10
// 54.525 us; speedup vs baseline: 4.1540x; 4.1540x over previous
//
#include <hip/hip_runtime.h>
#include <math.h>

// Problem constants
#define NSLOT 64
#define ADIM  256
#define NE    16
#define NCLS  100
#define BATCH 256

// ws layout (float offsets)
#define OFF_QK 0u           // [16][256][4]  qk[e][a][l], pre-scaled by 1/16
#define OFF_CP 16384u       // [16]          log1p(count+1)
#define OFF_U  32768u       // [16 e][256 b][256 a]   EXPERT-MAJOR
#define OFF_Z  1081344u     // [256 b][16 e][256 d]

__device__ __forceinline__ float wmax(float v) {
#pragma unroll
  for (int m = 32; m >= 1; m >>= 1) v = fmaxf(v, __shfl_xor(v, m, 64));
  return v;
}
__device__ __forceinline__ float wsum(float v) {
#pragma unroll
  for (int m = 32; m >= 1; m >>= 1) v += __shfl_xor(v, m, 64);
  return v;
}

// ---------------- K1: qk[e][a][l] = (1/16) * sum_d q[e,l,d]*Wk[e,d,a]
__global__ __launch_bounds__(256) void prep_kernel(
    const float* __restrict__ queries, const float* __restrict__ Wk,
    const int* __restrict__ counts, float* __restrict__ qk, float* __restrict__ cp)
{
  __shared__ float smf[1024];       // [dg16][a16][l4]
  const int e  = blockIdx.x;
  const int as = blockIdx.y;
  const int tid = threadIdx.x;
  const int a_loc = tid & 15, dg = tid >> 4;
  const float* __restrict__ qp  = queries + e * 1024 + dg * 16;
  const float* __restrict__ wkp = Wk + (size_t)e * 65536 + (size_t)(dg * 16) * 256 + as * 16 + a_loc;
  float a0 = 0.f, a1 = 0.f, a2 = 0.f, a3 = 0.f;
#pragma unroll
  for (int dd = 0; dd < 16; ++dd) {
    float w = wkp[(size_t)dd * 256];
    a0 += qp[0 * 256 + dd] * w;
    a1 += qp[1 * 256 + dd] * w;
    a2 += qp[2 * 256 + dd] * w;
    a3 += qp[3 * 256 + dd] * w;
  }
  float4 acc; acc.x = a0; acc.y = a1; acc.z = a2; acc.w = a3;
  *(float4*)&smf[tid * 4] = acc;
  __syncthreads();
  if (tid < 64) {
    float s = 0.f;
#pragma unroll
    for (int g = 0; g < 16; ++g) s += smf[g * 64 + tid];
    qk[e * 1024 + as * 64 + tid] = s * 0.0625f;
  }
  if (e == 0 && as == 0 && tid < 16) cp[tid] = log1pf((float)counts[tid] + 1.0f);
}

// ---------------- K2: per (b, expert-half): scores -> softmax -> p -> u
// 512 blocks x 512 threads, 66KB LDS -> 2 blocks/CU = 4 waves/SIMD.
// u stored EXPERT-MAJOR: U[e][b][a].
__global__ __launch_bounds__(512, 4) void attn_kernel(
    const float* __restrict__ x, const float* __restrict__ qk,
    float* __restrict__ U)
{
  __shared__ float Hs[64][256];   // chunk-swizzled: chunk c of row s at (c ^ (s&7))
  __shared__ float pt[64][8];
  const int tid  = threadIdx.x;
  const int lane = tid & 63;
  const int w    = tid >> 6;                 // 0..7
  const int i    = blockIdx.x;
  const int b    = i & 255;
  const int h    = i >> 8;                   // expert half

  const float4* __restrict__ x4 = (const float4*)(x + (size_t)b * 16384);
#pragma unroll
  for (int it = 0; it < 8; ++it) {
    int fidx = tid + it * 512;               // 0..4095 float4s
    int s = fidx >> 6, c = fidx & 63;
    *(float4*)&Hs[s][(c ^ (s & 7)) << 2] = x4[fidx];
  }
  __syncthreads();

  {
    const int e = __builtin_amdgcn_readfirstlane(h * 8 + w);
    const float* __restrict__ qe = qk + (size_t)e * 1024;
    float ac0 = 0.f, ac1 = 0.f, ac2 = 0.f, ac3 = 0.f;
#pragma unroll 4
    for (int a0 = 0; a0 < 64; ++a0) {
      float4 hh = *(const float4*)&Hs[lane][(a0 ^ (lane & 7)) << 2];
      const float4* __restrict__ qq = (const float4*)(qe + a0 * 16);
      float4 q0 = qq[0], q1 = qq[1], q2 = qq[2], q3 = qq[3];
      ac0 += hh.x*q0.x + hh.y*q1.x + hh.z*q2.x + hh.w*q3.x;
      ac1 += hh.x*q0.y + hh.y*q1.y + hh.z*q2.y + hh.w*q3.y;
      ac2 += hh.x*q0.z + hh.y*q1.z + hh.z*q2.z + hh.w*q3.z;
      ac3 += hh.x*q0.w + hh.y*q1.w + hh.z*q2.w + hh.w*q3.w;
    }
    float p = 0.f, m, ev;
    m = wmax(ac0); ev = __expf(ac0 - m); p += ev / wsum(ev);
    m = wmax(ac1); ev = __expf(ac1 - m); p += ev / wsum(ev);
    m = wmax(ac2); ev = __expf(ac2 - m); p += ev / wsum(ev);
    m = wmax(ac3); ev = __expf(ac3 - m); p += ev / wsum(ev);
    pt[lane][w] = p * 0.25f;
  }
  __syncthreads();

  {
    const int a = tid & 255, g = tid >> 8;
    const int hi = a >> 2, rem = a & 3;
    float u0 = 0.f, u1 = 0.f, u2 = 0.f, u3 = 0.f;
#pragma unroll 8
    for (int s = 0; s < 64; ++s) {
      float hv = Hs[s][(((hi ^ (s & 7)) << 2) | rem)];
      float4 p = *(const float4*)&pt[s][g * 4];
      u0 += hv * p.x; u1 += hv * p.y; u2 += hv * p.z; u3 += hv * p.w;
    }
    // expert-major store: U[e][b][a], e = h*8 + g*4 + j
    float* __restrict__ Ub = U + (size_t)(h * 8 + g * 4) * 65536 + (size_t)b * 256 + a;
    Ub[0 * 65536] = u0; Ub[1 * 65536] = u1; Ub[2 * 65536] = u2; Ub[3 * 65536] = u3;
  }
}

// ---------------- K3: per-expert GEMM  Z[b][e][d] = U[e][b][:] . Wv[e][d][:]
// U now dense per expert (256x256). Tile 64(b) x 32(d), K=256 in 4 chunks.
// grid 512: bt=i&3, dt=(i>>2)&7, e=i>>5. xcd = i%8 = bt + 4*(dt&1):
//   U-tile (e,bt) spans 2 XCDs; Wv-tile (e,dt) spans 4 XCDs.
__global__ __launch_bounds__(256, 2) void zgemm_kernel(
    const float* __restrict__ U, const float* __restrict__ Wv,
    float* __restrict__ Z)
{
  __shared__ float Us[64][64];   // chunk c of row r at (c ^ ((r>>2)&7))
  __shared__ float Ws[32][64];
  const int tid = threadIdx.x;
  const int i  = blockIdx.x;
  const int bt = i & 3, dt = (i >> 2) & 7, e = i >> 5;
  const int tx = tid & 15, ty = tid >> 4;
  float acc[4][2] = {};

  const float* __restrict__ Ua = U + (size_t)e * 65536 + (size_t)(bt * 64) * 256;
  const float* __restrict__ Wa = Wv + (size_t)e * 65536 + (size_t)(dt * 32) * 256;

  for (int ck = 0; ck < 4; ++ck) {
#pragma unroll
    for (int it = 0; it < 4; ++it) {
      int t2 = tid + it * 256;           // 0..1023
      int row = t2 >> 4, c = t2 & 15;
      *(float4*)&Us[row][(c ^ ((row >> 2) & 7)) << 2] =
        *(const float4*)&Ua[(size_t)row * 256 + ck * 64 + c * 4];
    }
#pragma unroll
    for (int it = 0; it < 2; ++it) {
      int t2 = tid + it * 256;           // 0..511
      int row = t2 >> 4, c = t2 & 15;
      *(float4*)&Ws[row][(c ^ ((row >> 2) & 7)) << 2] =
        *(const float4*)&Wa[(size_t)row * 256 + ck * 64 + c * 4];
    }
    __syncthreads();
#pragma unroll
    for (int cc = 0; cc < 16; ++cc) {
      float4 A[4], B[2];
#pragma unroll
      for (int ii = 0; ii < 4; ++ii) A[ii] = *(const float4*)&Us[ty * 4 + ii][(cc ^ (ty & 7)) << 2];
#pragma unroll
      for (int j = 0; j < 2; ++j) B[j] = *(const float4*)&Ws[tx * 2 + j][(cc ^ ((tx >> 1) & 7)) << 2];
#pragma unroll
      for (int ii = 0; ii < 4; ++ii)
#pragma unroll
        for (int j = 0; j < 2; ++j)
          acc[ii][j] += A[ii].x*B[j].x + A[ii].y*B[j].y + A[ii].z*B[j].z + A[ii].w*B[j].w;
    }
    __syncthreads();
  }

#pragma unroll
  for (int ii = 0; ii < 4; ++ii) {
    float2 r; r.x = acc[ii][0]; r.y = acc[ii][1];
    *(float2*)&Z[(((size_t)(bt * 64 + ty * 4 + ii)) * 16 + e) * 256 + dt * 32 + tx * 2] = r;
  }
}

// ---------------- K4: norms -> top3 -> gate -> final -> logits (single Z)
__global__ __launch_bounds__(512) void final_kernel(
    const float* __restrict__ Z, const float* __restrict__ cp,
    const float* __restrict__ CQ, float* __restrict__ out)
{
  __shared__ float zs[16][260];
  __shared__ float nrm[16];
  __shared__ float fin[256];
  const int tid = threadIdx.x, lane = tid & 63, w = tid >> 6;  // 8 waves
  const int b = blockIdx.x;
  const size_t zb = (size_t)b * 16 * 256;

#pragma unroll
  for (int it = 0; it < 2; ++it) {
    int idx = tid + it * 512;
    int e = idx >> 6, c = idx & 63;
    *(float4*)&zs[e][c * 4] = *(const float4*)&Z[zb + e * 256 + c * 4];
  }
  __syncthreads();

  for (int e = w; e < 16; e += 8) {
    float4 zv = *(const float4*)&zs[e][lane * 4];
    float ss = zv.x*zv.x + zv.y*zv.y + zv.z*zv.z + zv.w*zv.w;
    ss = wsum(ss);
    if (lane == 0) nrm[e] = sqrtf(ss);
  }
  __syncthreads();

  float sc[16];
#pragma unroll
  for (int e = 0; e < 16; ++e) sc[e] = nrm[e] * cp[e];
  int i0 = 0; float v0 = sc[0];
#pragma unroll
  for (int e = 1; e < 16; ++e) if (sc[e] > v0) { v0 = sc[e]; i0 = e; }
  int i1 = -1; float v1 = -3.4e38f;
#pragma unroll
  for (int e = 0; e < 16; ++e) if (e != i0 && sc[e] > v1) { v1 = sc[e]; i1 = e; }
  int i2 = -1; float v2 = -3.4e38f;
#pragma unroll
  for (int e = 0; e < 16; ++e) if (e != i0 && e != i1 && sc[e] > v2) { v2 = sc[e]; i2 = e; }
  float g1 = __expf(v1 - v0), g2 = __expf(v2 - v0);
  float inv = 1.0f / (1.0f + g1 + g2);
  float g0 = inv; g1 *= inv; g2 *= inv;

  if (tid < 256)
    fin[tid] = g0 * zs[i0][tid] + g1 * zs[i1][tid] + g2 * zs[i2][tid];
  __syncthreads();

  float4 f = *(const float4*)&fin[lane * 4];
  for (int c = w; c < NCLS; c += 8) {
    float4 cq = *(const float4*)&CQ[(size_t)c * 256 + lane * 4];
    float part = f.x*cq.x + f.y*cq.y + f.z*cq.z + f.w*cq.w;
    part = wsum(part);
    if (lane == 0) out[(size_t)b * NCLS + c] = part;
  }
}

extern "C" void kernel_launch(void* const* d_in, const int* in_sizes, int n_in,
                              void* d_out, int out_size, void* d_ws, size_t ws_size,
                              hipStream_t stream) {
  const float* x       = (const float*)d_in[0];
  const float* queries = (const float*)d_in[1];
  const float* Wk      = (const float*)d_in[2];
  const float* Wv      = (const float*)d_in[3];
  const float* CQ      = (const float*)d_in[4];
  const int*   counts  = (const int*)d_in[5];
  float* out = (float*)d_out;
  float* ws  = (float*)d_ws;
  float* qk = ws + OFF_QK;
  float* cp = ws + OFF_CP;
  float* U  = ws + OFF_U;
  float* Z  = ws + OFF_Z;

  prep_kernel<<<dim3(16, 16), 256, 0, stream>>>(queries, Wk, counts, qk, cp);
  attn_kernel<<<512, 512, 0, stream>>>(x, qk, U);
  zgemm_kernel<<<512, 256, 0, stream>>>(U, Wv, Z);
  final_kernel<<<256, 512, 0, stream>>>(Z, cp, CQ, out);
}